// Round 1
// baseline (2121.956 us; speedup 1.0000x reference)
//
#include <hip/hip_runtime.h>
#include <math.h>

#define BB 32
#define LL 128
#define DM 64
#define DI 128
#define DS 32
#define DTR 4
#define NV 50001
#define BL (BB*LL)   // 4096

// ---------------- stage 1: embedding ----------------
__global__ void k_embed(const int* __restrict__ ids, const float* __restrict__ item_emb,
                        const float* __restrict__ pos_emb, float* __restrict__ seqs) {
    int i = blockIdx.x * blockDim.x + threadIdx.x;   // over BL*DM
    if (i >= BL * DM) return;
    int row = i / DM, d = i % DM;
    int l = row % LL;
    int id = ids[row];
    float v = 0.0f;
    if (id != 0) v = item_emb[id * DM + d] * 8.0f + pos_emb[l * DM + d];
    seqs[i] = v;
}

// ---------------- stage 2: in_proj (4096x64 @ 64x256^T) ----------------
__global__ void k_inproj(const float* __restrict__ seqs, const float* __restrict__ w,
                         float* __restrict__ xz) {
    int row = blockIdx.x;
    int e = threadIdx.x;                 // 256 threads
    __shared__ float s[DM];
    if (threadIdx.x < DM) s[threadIdx.x] = seqs[row * DM + threadIdx.x];
    __syncthreads();
    float acc = 0.f;
    const float* wr = w + e * DM;
    #pragma unroll
    for (int d = 0; d < DM; d++) acc += s[d] * wr[d];
    xz[row * (2*DI) + e] = acc;
}

// ---------------- stage 3: causal depthwise conv + silu ----------------
__global__ void k_conv(const float* __restrict__ xz, const float* __restrict__ conv_w,
                       const float* __restrict__ conv_b, float* __restrict__ xcs) {
    int i = blockIdx.x * blockDim.x + threadIdx.x;   // over BL*DI
    if (i >= BL * DI) return;
    int c = i % DI;
    int row = i / DI;
    int l = row % LL;
    int base = row - l;                  // b*LL
    float acc = conv_b[c];
    #pragma unroll
    for (int k = 0; k < 4; k++) {
        int ll = l + k - 3;
        if (ll >= 0) acc += xz[(base + ll) * (2*DI) + c] * conv_w[c * 4 + k];
    }
    // silu
    xcs[i] = acc / (1.0f + expf(-acc));
}

// ---------------- stage 4: x_proj (-> dbl) + dt_proj + softplus (-> delta) ----------------
__global__ void k_xproj_delta(const float* __restrict__ xcs, const float* __restrict__ x_proj_w,
                              const float* __restrict__ dt_proj_w, const float* __restrict__ dt_proj_b,
                              float* __restrict__ dbl, float* __restrict__ delta) {
    int row = blockIdx.x;
    int t = threadIdx.x;                 // 128 threads
    __shared__ float xs[DI];
    __shared__ float dts[DTR];
    xs[t] = xcs[row * DI + t];
    __syncthreads();
    if (t < DTR + 2*DS) {                // 68
        float acc = 0.f;
        const float* wr = x_proj_w + t * DI;
        #pragma unroll
        for (int c = 0; c < DI; c++) acc += xs[c] * wr[c];
        dbl[row * 68 + t] = acc;
        if (t < DTR) dts[t] = acc;
    }
    __syncthreads();
    float acc = dt_proj_b[t];
    #pragma unroll
    for (int r = 0; r < DTR; r++) acc += dts[r] * dt_proj_w[t * DTR + r];
    float sp = (acc > 20.f) ? acc : log1pf(expf(acc));
    delta[row * DI + t] = sp;
}

// ---------------- stage 5: selective-scan over L, + D*xc, * silu(z) ----------------
// one 32-lane group per (b,c); lane = state s
__global__ void k_scan(const float* __restrict__ delta, const float* __restrict__ dbl,
                       const float* __restrict__ xcs, const float* __restrict__ xz,
                       const float* __restrict__ A_log, const float* __restrict__ Dp,
                       float* __restrict__ y) {
    int g = blockIdx.x * (blockDim.x / 32) + (threadIdx.x / 32);  // 0..BB*DI-1
    if (g >= BB * DI) return;
    int b = g / DI, c = g % DI;
    int s = threadIdx.x & 31;
    float Acs = -expf(A_log[c * DS + s]);
    float Dc = Dp[c];
    float h = 0.f;
    for (int t = 0; t < LL; t++) {
        int row = b * LL + t;
        float dlt = delta[row * DI + c];
        float xct = xcs[row * DI + c];
        float Bt = dbl[row * 68 + DTR + s];
        float Ct = dbl[row * 68 + DTR + DS + s];
        h = expf(dlt * Acs) * h + dlt * Bt * xct;
        float p = h * Ct;
        #pragma unroll
        for (int off = 16; off; off >>= 1) p += __shfl_xor(p, off, 32);
        if (s == 0) {
            float zt = xz[row * (2*DI) + DI + c];
            float yv = (p + Dc * xct) * (zt / (1.0f + expf(-zt)));
            y[row * DI + c] = yv;
        }
    }
}

// ---------------- stage 6: out_proj (4096x128 @ 128x64^T) ----------------
__global__ void k_outproj(const float* __restrict__ y, const float* __restrict__ w,
                          float* __restrict__ outp) {
    int row = blockIdx.x;
    int d = threadIdx.x;                 // 64 threads
    __shared__ float ys[DI];
    ys[d] = y[row * DI + d];
    ys[d + 64] = y[row * DI + d + 64];
    __syncthreads();
    float acc = 0.f;
    const float* wr = w + d * DI;
    #pragma unroll
    for (int c = 0; c < DI; c++) acc += ys[c] * wr[c];
    outp[row * DM + d] = acc;
}

// ---------------- stage 7: logits GEMM: (4096x64) @ (50001x64)^T ----------------
// 64x64 tile per block, 256 threads, 4x4 micro-tile per thread (cols strided by 16)
__global__ __launch_bounds__(256) void k_logits(const float* __restrict__ outp,
                                                const float* __restrict__ emb,
                                                float* __restrict__ logits) {
    __shared__ float As[64][68];
    __shared__ float Bs[64][68];
    int m0 = blockIdx.y * 64;
    int n0 = blockIdx.x * 64;
    int tid = threadIdx.x;

    // load A tile (64 rows x 64 cols), float4-coalesced
    #pragma unroll
    for (int q = 0; q < 4; q++) {
        int flat = tid + q * 256;        // float4 index
        int r = flat >> 4, c4 = flat & 15;
        float4 v = *reinterpret_cast<const float4*>(outp + (m0 + r) * DM + c4 * 4);
        *reinterpret_cast<float4*>(&As[r][c4 * 4]) = v;
    }
    // load B tile (item_emb rows n0..n0+63), zero-pad OOB
    #pragma unroll
    for (int q = 0; q < 4; q++) {
        int flat = tid + q * 256;
        int r = flat >> 4, c4 = flat & 15;
        int vr = n0 + r;
        float4 v = make_float4(0.f, 0.f, 0.f, 0.f);
        if (vr < NV) v = *reinterpret_cast<const float4*>(emb + vr * DM + c4 * 4);
        *reinterpret_cast<float4*>(&Bs[r][c4 * 4]) = v;
    }
    __syncthreads();

    int tx = tid & 15, ty = tid >> 4;
    float acc[4][4] = {};
    #pragma unroll
    for (int k4 = 0; k4 < 16; k4++) {
        float4 a[4], b[4];
        #pragma unroll
        for (int i = 0; i < 4; i++)
            a[i] = *reinterpret_cast<const float4*>(&As[ty * 4 + i][k4 * 4]);
        #pragma unroll
        for (int j = 0; j < 4; j++)
            b[j] = *reinterpret_cast<const float4*>(&Bs[tx + 16 * j][k4 * 4]);
        #pragma unroll
        for (int i = 0; i < 4; i++)
            #pragma unroll
            for (int j = 0; j < 4; j++)
                acc[i][j] += a[i].x * b[j].x + a[i].y * b[j].y
                           + a[i].z * b[j].z + a[i].w * b[j].w;
    }

    // store: col n = n0 + tx + 16*j -> per-instruction 16 consecutive floats per 16 lanes
    #pragma unroll
    for (int i = 0; i < 4; i++) {
        int m = m0 + ty * 4 + i;
        float* dst = logits + (size_t)m * NV;
        #pragma unroll
        for (int j = 0; j < 4; j++) {
            int n = n0 + tx + 16 * j;
            if (n < NV) dst[n] = acc[i][j];
        }
    }
}

extern "C" void kernel_launch(void* const* d_in, const int* in_sizes, int n_in,
                              void* d_out, int out_size, void* d_ws, size_t ws_size,
                              hipStream_t stream) {
    const int*   ids       = (const int*)  d_in[0];
    const float* item_emb  = (const float*)d_in[1];
    const float* pos_emb   = (const float*)d_in[2];
    const float* in_proj_w = (const float*)d_in[3];
    const float* conv_w    = (const float*)d_in[4];
    const float* conv_b    = (const float*)d_in[5];
    const float* x_proj_w  = (const float*)d_in[6];
    const float* dt_proj_w = (const float*)d_in[7];
    const float* dt_proj_b = (const float*)d_in[8];
    const float* A_log     = (const float*)d_in[9];
    const float* Dp        = (const float*)d_in[10];
    const float* out_proj_w= (const float*)d_in[11];
    float* logits = (float*)d_out;

    float* ws    = (float*)d_ws;
    float* seqs  = ws;                    // BL*64
    float* xz    = seqs  + BL * DM;       // BL*256
    float* xcs   = xz    + BL * 2 * DI;   // BL*128
    float* dbl   = xcs   + BL * DI;       // BL*68
    float* delta = dbl   + BL * 68;       // BL*128
    float* y     = delta + BL * DI;       // BL*128
    float* outp  = y     + BL * DI;       // BL*64

    k_embed<<<(BL * DM + 255) / 256, 256, 0, stream>>>(ids, item_emb, pos_emb, seqs);
    k_inproj<<<BL, 256, 0, stream>>>(seqs, in_proj_w, xz);
    k_conv<<<(BL * DI + 255) / 256, 256, 0, stream>>>(xz, conv_w, conv_b, xcs);
    k_xproj_delta<<<BL, 128, 0, stream>>>(xcs, x_proj_w, dt_proj_w, dt_proj_b, dbl, delta);
    k_scan<<<(BB * DI) / 8, 256, 0, stream>>>(delta, dbl, xcs, xz, A_log, Dp, y);
    k_outproj<<<BL, 64, 0, stream>>>(y, out_proj_w, outp);
    dim3 lg((NV + 63) / 64, BL / 64);
    k_logits<<<lg, 256, 0, stream>>>(outp, item_emb, logits);
}

// Round 2
// 784.727 us; speedup vs baseline: 2.7041x; 2.7041x over previous
//
#include <hip/hip_runtime.h>
#include <math.h>

#define BB 32
#define LL 128
#define DM 64
#define DI 128
#define DS 32
#define DTR 4
#define NV 50001
#define BL (BB*LL)   // 4096

// ---------------- stage 1: embedding ----------------
__global__ void k_embed(const int* __restrict__ ids, const float* __restrict__ item_emb,
                        const float* __restrict__ pos_emb, float* __restrict__ seqs) {
    int i = blockIdx.x * blockDim.x + threadIdx.x;   // over BL*DM
    if (i >= BL * DM) return;
    int row = i / DM, d = i % DM;
    int l = row % LL;
    int id = ids[row];
    float v = 0.0f;
    if (id != 0) v = item_emb[id * DM + d] * 8.0f + pos_emb[l * DM + d];
    seqs[i] = v;
}

// ---------------- stage 2: in_proj (4096x64 @ 64x256^T) ----------------
__global__ void k_inproj(const float* __restrict__ seqs, const float* __restrict__ w,
                         float* __restrict__ xz) {
    int row = blockIdx.x;
    int e = threadIdx.x;                 // 256 threads
    __shared__ float s[DM];
    if (threadIdx.x < DM) s[threadIdx.x] = seqs[row * DM + threadIdx.x];
    __syncthreads();
    float acc = 0.f;
    const float* wr = w + e * DM;
    #pragma unroll
    for (int d = 0; d < DM; d++) acc += s[d] * wr[d];
    xz[row * (2*DI) + e] = acc;
}

// ---------------- stage 3: causal depthwise conv + silu ----------------
__global__ void k_conv(const float* __restrict__ xz, const float* __restrict__ conv_w,
                       const float* __restrict__ conv_b, float* __restrict__ xcs) {
    int i = blockIdx.x * blockDim.x + threadIdx.x;   // over BL*DI
    if (i >= BL * DI) return;
    int c = i % DI;
    int row = i / DI;
    int l = row % LL;
    int base = row - l;                  // b*LL
    float acc = conv_b[c];
    #pragma unroll
    for (int k = 0; k < 4; k++) {
        int ll = l + k - 3;
        if (ll >= 0) acc += xz[(base + ll) * (2*DI) + c] * conv_w[c * 4 + k];
    }
    // silu
    xcs[i] = acc / (1.0f + expf(-acc));
}

// ---------------- stage 4: x_proj (-> dbl) + dt_proj + softplus (-> delta) ----------------
__global__ void k_xproj_delta(const float* __restrict__ xcs, const float* __restrict__ x_proj_w,
                              const float* __restrict__ dt_proj_w, const float* __restrict__ dt_proj_b,
                              float* __restrict__ dbl, float* __restrict__ delta) {
    int row = blockIdx.x;
    int t = threadIdx.x;                 // 128 threads
    __shared__ float xs[DI];
    __shared__ float dts[DTR];
    xs[t] = xcs[row * DI + t];
    __syncthreads();
    if (t < DTR + 2*DS) {                // 68
        float acc = 0.f;
        const float* wr = x_proj_w + t * DI;
        #pragma unroll
        for (int c = 0; c < DI; c++) acc += xs[c] * wr[c];
        dbl[row * 68 + t] = acc;
        if (t < DTR) dts[t] = acc;
    }
    __syncthreads();
    float acc = dt_proj_b[t];
    #pragma unroll
    for (int r = 0; r < DTR; r++) acc += dts[r] * dt_proj_w[t * DTR + r];
    float sp = (acc > 20.f) ? acc : log1pf(expf(acc));
    delta[row * DI + t] = sp;
}

// ---------------- stage 5: selective-scan over L, + D*xc, * silu(z) ----------------
// one 32-lane group per (b,c); lane = state s
__global__ void k_scan(const float* __restrict__ delta, const float* __restrict__ dbl,
                       const float* __restrict__ xcs, const float* __restrict__ xz,
                       const float* __restrict__ A_log, const float* __restrict__ Dp,
                       float* __restrict__ y) {
    int g = blockIdx.x * (blockDim.x / 32) + (threadIdx.x / 32);  // 0..BB*DI-1
    if (g >= BB * DI) return;
    int b = g / DI, c = g % DI;
    int s = threadIdx.x & 31;
    float Acs = -expf(A_log[c * DS + s]);
    float Dc = Dp[c];
    float h = 0.f;
    for (int t = 0; t < LL; t++) {
        int row = b * LL + t;
        float dlt = delta[row * DI + c];
        float xct = xcs[row * DI + c];
        float Bt = dbl[row * 68 + DTR + s];
        float Ct = dbl[row * 68 + DTR + DS + s];
        h = expf(dlt * Acs) * h + dlt * Bt * xct;
        float p = h * Ct;
        #pragma unroll
        for (int off = 16; off; off >>= 1) p += __shfl_xor(p, off, 32);
        if (s == 0) {
            float zt = xz[row * (2*DI) + DI + c];
            float yv = (p + Dc * xct) * (zt / (1.0f + expf(-zt)));
            y[row * DI + c] = yv;
        }
    }
}

// ---------------- stage 6: out_proj (4096x128 @ 128x64^T) ----------------
__global__ void k_outproj(const float* __restrict__ y, const float* __restrict__ w,
                          float* __restrict__ outp) {
    int row = blockIdx.x;
    int d = threadIdx.x;                 // 64 threads
    __shared__ float ys[DI];
    ys[d] = y[row * DI + d];
    ys[d + 64] = y[row * DI + d + 64];
    __syncthreads();
    float acc = 0.f;
    const float* wr = w + d * DI;
    #pragma unroll
    for (int c = 0; c < DI; c++) acc += ys[c] * wr[c];
    outp[row * DM + d] = acc;
}

// ---------------- stage 7: logits GEMM: (4096x64) @ (50001x64)^T ----------------
// Each thread owns ONE output column n (coalesced stores), 32 rows m.
// B[n][k] staged via LDS (stride-33 rows: bank = (t+k)%32, conflict-free),
// then held in 32 registers per K-half. A values are wave-uniform loads
// (scalar pipe) -> inner loop is pure v_fmac.
#define TGN 256   // n per block
#define TGM 32    // m per block
__global__ __launch_bounds__(256, 4) void k_logits(const float* __restrict__ outp,
                                                   const float* __restrict__ emb,
                                                   float* __restrict__ logits) {
    __shared__ float Bs[TGN * 33];
    const int m0 = blockIdx.x * TGM;
    const int n0 = blockIdx.y * TGN;
    const int t  = threadIdx.x;
    const int n  = n0 + t;

    float acc[TGM];
    #pragma unroll
    for (int m = 0; m < TGM; m++) acc[m] = 0.f;

    for (int kk = 0; kk < DM; kk += 32) {
        // ---- stage B half-tile: rows n0..n0+255, cols kk..kk+31 ----
        #pragma unroll
        for (int q = 0; q < 8; q++) {
            int idx = t + q * 256;           // float4 index in 256x8
            int r = idx >> 3, c4 = idx & 7;
            int vr = n0 + r;
            float4 v = make_float4(0.f, 0.f, 0.f, 0.f);
            if (vr < NV) v = *reinterpret_cast<const float4*>(emb + vr * DM + kk + c4 * 4);
            float* row = Bs + r * 33 + c4 * 4;
            row[0] = v.x; row[1] = v.y; row[2] = v.z; row[3] = v.w;
        }
        __syncthreads();

        // ---- pull my column's 32 B values into registers ----
        float b[32];
        #pragma unroll
        for (int k = 0; k < 32; k++) b[k] = Bs[t * 33 + k];

        // ---- A is wave-uniform: scalar loads + pure FMA ----
        #pragma unroll
        for (int m = 0; m < TGM; m++) {
            const float* ap = outp + (m0 + m) * DM + kk;
            float a = acc[m];
            #pragma unroll
            for (int j = 0; j < 8; j++) {
                float4 av = *reinterpret_cast<const float4*>(ap + j * 4);
                a += av.x * b[j*4+0] + av.y * b[j*4+1] + av.z * b[j*4+2] + av.w * b[j*4+3];
            }
            acc[m] = a;
        }
        __syncthreads();
    }

    if (n < NV) {
        #pragma unroll
        for (int m = 0; m < TGM; m++)
            logits[(size_t)(m0 + m) * NV + n] = acc[m];
    }
}

extern "C" void kernel_launch(void* const* d_in, const int* in_sizes, int n_in,
                              void* d_out, int out_size, void* d_ws, size_t ws_size,
                              hipStream_t stream) {
    const int*   ids       = (const int*)  d_in[0];
    const float* item_emb  = (const float*)d_in[1];
    const float* pos_emb   = (const float*)d_in[2];
    const float* in_proj_w = (const float*)d_in[3];
    const float* conv_w    = (const float*)d_in[4];
    const float* conv_b    = (const float*)d_in[5];
    const float* x_proj_w  = (const float*)d_in[6];
    const float* dt_proj_w = (const float*)d_in[7];
    const float* dt_proj_b = (const float*)d_in[8];
    const float* A_log     = (const float*)d_in[9];
    const float* Dp        = (const float*)d_in[10];
    const float* out_proj_w= (const float*)d_in[11];
    float* logits = (float*)d_out;

    float* ws    = (float*)d_ws;
    float* seqs  = ws;                    // BL*64
    float* xz    = seqs  + BL * DM;       // BL*256
    float* xcs   = xz    + BL * 2 * DI;   // BL*128
    float* dbl   = xcs   + BL * DI;       // BL*68
    float* delta = dbl   + BL * 68;       // BL*128
    float* y     = delta + BL * DI;       // BL*128
    float* outp  = y     + BL * DI;       // BL*64

    k_embed<<<(BL * DM + 255) / 256, 256, 0, stream>>>(ids, item_emb, pos_emb, seqs);
    k_inproj<<<BL, 256, 0, stream>>>(seqs, in_proj_w, xz);
    k_conv<<<(BL * DI + 255) / 256, 256, 0, stream>>>(xz, conv_w, conv_b, xcs);
    k_xproj_delta<<<BL, 128, 0, stream>>>(xcs, x_proj_w, dt_proj_w, dt_proj_b, dbl, delta);
    k_scan<<<(BB * DI) / 8, 256, 0, stream>>>(delta, dbl, xcs, xz, A_log, Dp, y);
    k_outproj<<<BL, 64, 0, stream>>>(y, out_proj_w, outp);

    dim3 lg(BL / TGM, (NV + TGN - 1) / TGN);   // x = m-blocks (128), y = n-blocks (196)
    k_logits<<<lg, 256, 0, stream>>>(outp, item_emb, logits);
}

// Round 3
// 469.235 us; speedup vs baseline: 4.5222x; 1.6724x over previous
//
#include <hip/hip_runtime.h>
#include <math.h>

#define BB 32
#define LL 128
#define DM 64
#define DI 128
#define DS 32
#define DTR 4
#define NV 50001
#define BL (BB*LL)   // 4096
#define NBLK 391     // ceil(50001/128)
#define NPAD (NBLK*128)  // 50048

typedef short bf16x8 __attribute__((ext_vector_type(8)));
typedef float f32x4 __attribute__((ext_vector_type(4)));

__device__ __forceinline__ unsigned short f2bf_rne(float x) {
    unsigned u = __builtin_bit_cast(unsigned, x);
    unsigned r = u + 0x7FFFu + ((u >> 16) & 1u);
    return (unsigned short)(r >> 16);
}
__device__ __forceinline__ float bf2f(unsigned short h) {
    unsigned u = ((unsigned)h) << 16;
    return __builtin_bit_cast(float, u);
}

// ---------------- stage 1: embedding ----------------
__global__ void k_embed(const int* __restrict__ ids, const float* __restrict__ item_emb,
                        const float* __restrict__ pos_emb, float* __restrict__ seqs) {
    int i = blockIdx.x * blockDim.x + threadIdx.x;   // over BL*DM
    if (i >= BL * DM) return;
    int row = i / DM, d = i % DM;
    int l = row % LL;
    int id = ids[row];
    float v = 0.0f;
    if (id != 0) v = item_emb[id * DM + d] * 8.0f + pos_emb[l * DM + d];
    seqs[i] = v;
}

// ---------------- stage 2: in_proj ----------------
__global__ void k_inproj(const float* __restrict__ seqs, const float* __restrict__ w,
                         float* __restrict__ xz) {
    int row = blockIdx.x;
    int e = threadIdx.x;                 // 256 threads
    __shared__ float s[DM];
    if (threadIdx.x < DM) s[threadIdx.x] = seqs[row * DM + threadIdx.x];
    __syncthreads();
    float acc = 0.f;
    const float* wr = w + e * DM;
    #pragma unroll
    for (int d = 0; d < DM; d++) acc += s[d] * wr[d];
    xz[row * (2*DI) + e] = acc;
}

// ---------------- stage 3: causal depthwise conv + silu ----------------
__global__ void k_conv(const float* __restrict__ xz, const float* __restrict__ conv_w,
                       const float* __restrict__ conv_b, float* __restrict__ xcs) {
    int i = blockIdx.x * blockDim.x + threadIdx.x;   // over BL*DI
    if (i >= BL * DI) return;
    int c = i % DI;
    int row = i / DI;
    int l = row % LL;
    int base = row - l;                  // b*LL
    float acc = conv_b[c];
    #pragma unroll
    for (int k = 0; k < 4; k++) {
        int ll = l + k - 3;
        if (ll >= 0) acc += xz[(base + ll) * (2*DI) + c] * conv_w[c * 4 + k];
    }
    xcs[i] = acc / (1.0f + expf(-acc));
}

// ---------------- stage 4: x_proj + dt_proj + softplus ----------------
__global__ void k_xproj_delta(const float* __restrict__ xcs, const float* __restrict__ x_proj_w,
                              const float* __restrict__ dt_proj_w, const float* __restrict__ dt_proj_b,
                              float* __restrict__ dbl, float* __restrict__ delta) {
    int row = blockIdx.x;
    int t = threadIdx.x;                 // 128 threads
    __shared__ float xs[DI];
    __shared__ float dts[DTR];
    xs[t] = xcs[row * DI + t];
    __syncthreads();
    if (t < DTR + 2*DS) {                // 68
        float acc = 0.f;
        const float* wr = x_proj_w + t * DI;
        #pragma unroll
        for (int c = 0; c < DI; c++) acc += xs[c] * wr[c];
        dbl[row * 68 + t] = acc;
        if (t < DTR) dts[t] = acc;
    }
    __syncthreads();
    float acc = dt_proj_b[t];
    #pragma unroll
    for (int r = 0; r < DTR; r++) acc += dts[r] * dt_proj_w[t * DTR + r];
    float sp = (acc > 20.f) ? acc : log1pf(expf(acc));
    delta[row * DI + t] = sp;
}

// ---------------- stage 5: selective scan ----------------
__global__ void k_scan(const float* __restrict__ delta, const float* __restrict__ dbl,
                       const float* __restrict__ xcs, const float* __restrict__ xz,
                       const float* __restrict__ A_log, const float* __restrict__ Dp,
                       float* __restrict__ y) {
    int g = blockIdx.x * (blockDim.x / 32) + (threadIdx.x / 32);  // 0..BB*DI-1
    if (g >= BB * DI) return;
    int b = g / DI, c = g % DI;
    int s = threadIdx.x & 31;
    float Acs = -expf(A_log[c * DS + s]);
    float Dc = Dp[c];
    float h = 0.f;
    for (int t = 0; t < LL; t++) {
        int row = b * LL + t;
        float dlt = delta[row * DI + c];
        float xct = xcs[row * DI + c];
        float Bt = dbl[row * 68 + DTR + s];
        float Ct = dbl[row * 68 + DTR + DS + s];
        h = expf(dlt * Acs) * h + dlt * Bt * xct;
        float p = h * Ct;
        #pragma unroll
        for (int off = 16; off; off >>= 1) p += __shfl_xor(p, off, 32);
        if (s == 0) {
            float zt = xz[row * (2*DI) + DI + c];
            float yv = (p + Dc * xct) * (zt / (1.0f + expf(-zt)));
            y[row * DI + c] = yv;
        }
    }
}

// ---------------- stage 6: out_proj -> bf16 hi/lo directly ----------------
__global__ void k_outproj(const float* __restrict__ y, const float* __restrict__ w,
                          unsigned short* __restrict__ outp2) {
    int row = blockIdx.x;
    int d = threadIdx.x;                 // 64 threads
    __shared__ float ys[DI];
    ys[d] = y[row * DI + d];
    ys[d + 64] = y[row * DI + d + 64];
    __syncthreads();
    float acc = 0.f;
    const float* wr = w + d * DI;
    #pragma unroll
    for (int c = 0; c < DI; c++) acc += ys[c] * wr[c];
    unsigned short hi = f2bf_rne(acc);
    unsigned short lo = f2bf_rne(acc - bf2f(hi));
    outp2[row * 128 + d] = hi;
    outp2[row * 128 + 64 + d] = lo;
}

// ---------------- emb -> bf16 hi/lo ----------------
__global__ void k_cvt_emb(const float* __restrict__ emb, unsigned short* __restrict__ emb2) {
    int i = blockIdx.x * blockDim.x + threadIdx.x;   // over NPAD*64
    if (i >= NPAD * 64) return;
    int r = i >> 6, d = i & 63;
    unsigned short hi = 0, lo = 0;
    if (r < NV) {
        float x = emb[r * 64 + d];
        hi = f2bf_rne(x);
        lo = f2bf_rne(x - bf2f(hi));
    }
    emb2[r * 128 + d] = hi;
    emb2[r * 128 + 64 + d] = lo;
}

// ---------------- stage 7: logits via MFMA, K=192 split-bf16 ----------------
// A' = [Ahi | Alo | Ahi], B' = [Bhi | Bhi | Blo]  ->  Ahi*Bhi + Alo*Bhi + Ahi*Blo
// block: 256 thr = 4 waves; tile M=64 x N=128; wave w covers cols 32w..32w+31
#define LTM 64
#define LTN 128
#define LDP 200   // padded LDS row pitch in bf16 (400 B -> bank (4r)%32, <=2-way)

__global__ __launch_bounds__(256, 2) void k_logits(const unsigned short* __restrict__ outp2,
                                                   const unsigned short* __restrict__ emb2,
                                                   float* __restrict__ logits) {
    __shared__ unsigned short As[LTM * LDP];
    __shared__ unsigned short Bs[LTN * LDP];
    const int m0 = blockIdx.x * LTM;
    const int n0 = blockIdx.y * LTN;
    const int t = threadIdx.x;

    // stage A': 64 rows x 192 cols -> 1536 16B-chunks, 6 per thread
    #pragma unroll
    for (int q = 0; q < 6; q++) {
        int ci = t + q * 256;
        int r = ci / 24, c8 = ci % 24;
        int k = c8 * 8;
        int sc = (k < 128) ? k : (k - 128);
        bf16x8 v = *reinterpret_cast<const bf16x8*>(outp2 + (m0 + r) * 128 + sc);
        *reinterpret_cast<bf16x8*>(&As[r * LDP + k]) = v;
    }
    // stage B': 128 rows x 192 cols -> 3072 chunks, 12 per thread
    #pragma unroll
    for (int q = 0; q < 12; q++) {
        int ci = t + q * 256;
        int r = ci / 24, c8 = ci % 24;
        int k = c8 * 8;
        int sc = (k < 64) ? k : (k - 64);
        bf16x8 v = *reinterpret_cast<const bf16x8*>(emb2 + (n0 + r) * 128 + sc);
        *reinterpret_cast<bf16x8*>(&Bs[r * LDP + k]) = v;
    }
    __syncthreads();

    const int lane = t & 63, wv = t >> 6;
    const int lr = lane & 15, lg = lane >> 4;   // row-in-16, k-group

    f32x4 acc[4][2];
    #pragma unroll
    for (int mi = 0; mi < 4; mi++)
        #pragma unroll
        for (int ni = 0; ni < 2; ni++)
            acc[mi][ni] = f32x4{0.f, 0.f, 0.f, 0.f};

    #pragma unroll
    for (int step = 0; step < 6; step++) {
        int kb = step * 32 + lg * 8;
        bf16x8 a[4], b[2];
        #pragma unroll
        for (int mi = 0; mi < 4; mi++)
            a[mi] = *reinterpret_cast<const bf16x8*>(&As[(16 * mi + lr) * LDP + kb]);
        #pragma unroll
        for (int ni = 0; ni < 2; ni++)
            b[ni] = *reinterpret_cast<const bf16x8*>(&Bs[(32 * wv + 16 * ni + lr) * LDP + kb]);
        #pragma unroll
        for (int mi = 0; mi < 4; mi++)
            #pragma unroll
            for (int ni = 0; ni < 2; ni++)
                acc[mi][ni] = __builtin_amdgcn_mfma_f32_16x16x32_bf16(a[mi], b[ni], acc[mi][ni], 0, 0, 0);
    }

    // store: C/D layout col=lane&15, row=4*(lane>>4)+reg  [m89-verified]
    #pragma unroll
    for (int mi = 0; mi < 4; mi++) {
        #pragma unroll
        for (int ni = 0; ni < 2; ni++) {
            int col = n0 + 32 * wv + 16 * ni + lr;
            if (col < NV) {
                #pragma unroll
                for (int j = 0; j < 4; j++) {
                    int row = m0 + 16 * mi + 4 * lg + j;
                    logits[(size_t)row * NV + col] = acc[mi][ni][j];
                }
            }
        }
    }
}

extern "C" void kernel_launch(void* const* d_in, const int* in_sizes, int n_in,
                              void* d_out, int out_size, void* d_ws, size_t ws_size,
                              hipStream_t stream) {
    const int*   ids       = (const int*)  d_in[0];
    const float* item_emb  = (const float*)d_in[1];
    const float* pos_emb   = (const float*)d_in[2];
    const float* in_proj_w = (const float*)d_in[3];
    const float* conv_w    = (const float*)d_in[4];
    const float* conv_b    = (const float*)d_in[5];
    const float* x_proj_w  = (const float*)d_in[6];
    const float* dt_proj_w = (const float*)d_in[7];
    const float* dt_proj_b = (const float*)d_in[8];
    const float* A_log     = (const float*)d_in[9];
    const float* Dp        = (const float*)d_in[10];
    const float* out_proj_w= (const float*)d_in[11];
    float* logits = (float*)d_out;

    float* ws    = (float*)d_ws;
    float* seqs  = ws;                    // BL*64
    float* xz    = seqs  + BL * DM;       // BL*256
    float* xcs   = xz    + BL * 2 * DI;   // BL*128
    float* dbl   = xcs   + BL * DI;       // BL*68
    float* delta = dbl   + BL * 68;       // BL*128
    float* y     = delta + BL * DI;       // BL*128
    unsigned short* outp2 = (unsigned short*)(y + BL * DI);   // BL*128 bf16
    unsigned short* emb2  = outp2 + BL * 128;                 // NPAD*128 bf16

    k_cvt_emb<<<(NPAD * 64 + 255) / 256, 256, 0, stream>>>(item_emb, emb2);
    k_embed<<<(BL * DM + 255) / 256, 256, 0, stream>>>(ids, item_emb, pos_emb, seqs);
    k_inproj<<<BL, 256, 0, stream>>>(seqs, in_proj_w, xz);
    k_conv<<<(BL * DI + 255) / 256, 256, 0, stream>>>(xz, conv_w, conv_b, xcs);
    k_xproj_delta<<<BL, 128, 0, stream>>>(xcs, x_proj_w, dt_proj_w, dt_proj_b, dbl, delta);
    k_scan<<<(BB * DI) / 8, 256, 0, stream>>>(delta, dbl, xcs, xz, A_log, Dp, y);
    k_outproj<<<BL, 64, 0, stream>>>(y, out_proj_w, outp2);

    dim3 lg(BL / LTM, NBLK);   // x = 64 m-blocks (fastest, shares B tile), y = 391 n-blocks
    k_logits<<<lg, 256, 0, stream>>>(outp2, emb2, logits);
}